// Round 3
// baseline (88.323 us; speedup 1.0000x reference)
//
#include <hip/hip_runtime.h>
#include <cstdint>
#include <cstddef>

// Problem constants (from reference)
constexpr int B = 8, C = 96, N = 3136, K = 18;
constexpr float C1c = 1e-6f, C2c = 1e-6f;

__device__ inline float readlane_f(float v, int l) {
  return __builtin_bit_cast(float,
                            __builtin_amdgcn_readlane(__builtin_bit_cast(int, v), l));
}

// ---------------------------------------------------------------------------
// Kernel A: tiled transpose of x and x_p: [B,C,N] -> [B,N,C]
// ---------------------------------------------------------------------------
__global__ __launch_bounds__(256) void transpose2_kernel(
    const float* __restrict__ x, const float* __restrict__ xp,
    float* __restrict__ xT, float* __restrict__ xpT) {
  __shared__ float t0[32][33];
  __shared__ float t1[32][33];
  const int b = blockIdx.z;
  const int c0 = blockIdx.y * 32;
  const int n0 = blockIdx.x * 32;
  const int tx = threadIdx.x, ty = threadIdx.y;  // block (32, 8)
  const float* xb = x + (size_t)b * C * N;
  const float* xpb = xp + (size_t)b * C * N;
#pragma unroll
  for (int i = 0; i < 4; ++i) {
    const int c = c0 + ty + i * 8;
    t0[ty + i * 8][tx] = xb[(size_t)c * N + n0 + tx];
    t1[ty + i * 8][tx] = xpb[(size_t)c * N + n0 + tx];
  }
  __syncthreads();
  float* xTb = xT + (size_t)b * N * C;
  float* xpTb = xpT + (size_t)b * N * C;
#pragma unroll
  for (int i = 0; i < 4; ++i) {
    const int n = n0 + ty + i * 8;
    xTb[(size_t)n * C + c0 + tx] = t0[tx][ty + i * 8];
    xpTb[(size_t)n * C + c0 + tx] = t1[tx][ty + i * 8];
  }
}

// ---------------------------------------------------------------------------
// Kernel B: per-column raw sums of x over channels: cstat[b*N+m] = {Σx, Σx²}
// ---------------------------------------------------------------------------
__global__ __launch_bounds__(256) void colstats_kernel(
    const float* __restrict__ x, float2* __restrict__ cstat) {
  const int idx = blockIdx.x * 256 + threadIdx.x;  // b*N + m
  if (idx >= B * N) return;
  const int b = idx / N;
  const int m = idx - b * N;
  const float* p = x + (size_t)b * C * N + m;
  float s = 0.f, s2 = 0.f;
#pragma unroll 4
  for (int c = 0; c < C; ++c) {
    const float v = p[(size_t)c * N];
    s += v;
    s2 += v * v;
  }
  cstat[idx] = make_float2(s, s2);
}

// ---------------------------------------------------------------------------
// Kernel C: main fused kernel. One wave per (b,n); batch pinned to XCD via
// blockIdx & 7. Lane l (<48) owns channels {2l, 2l+1} -> each gathered
// column is ONE global_load_dwordx2 (exactly 384B). Dot partials for all 18
// k's are reduced with a logarithmic pairing tree: each butterfly level
// merges two k-partials into one register (lane bit at distance D selects
// which k a lane carries), so 18 full sums cost 21 shuffles instead of 108.
// Final sums land at known lanes (LK table), broadcast via readlane; sff is
// computed on wave-uniform values; output written directly to out[B,C,N]
// (scattered dwords absorbed by XCD-local L2).
// ---------------------------------------------------------------------------
__global__ __launch_bounds__(256) void ssim_main_kernel(
    const float* __restrict__ xT, const float* __restrict__ xpT,
    const float2* __restrict__ cstat, const int* __restrict__ eidx,
    float* __restrict__ out) {
  const int wave = threadIdx.x >> 6;
  const int lane = threadIdx.x & 63;
  const int b = blockIdx.x & 7;          // XCD pin: batch == blockIdx % 8
  const int tile = blockIdx.x >> 3;
  const int n = tile * 4 + wave;

  // lanes 0..17 -> j_k (edge_index[0]), lanes 18..35 -> i_k (edge_index[1])
  int myidx = 0;
  if (lane < 36) {
    const int s = (lane >= 18) ? 1 : 0;
    const int k = lane - 18 * s;
    myidx = eidx[((size_t)(s * B + b) * N + n) * K + k];
  }

  int ji[K], jj[K];  // wave-uniform (SGPR) column indices
#pragma unroll
  for (int k = 0; k < K; ++k) {
    jj[k] = __builtin_amdgcn_readlane(myidx, k);
    ji[k] = __builtin_amdgcn_readlane(myidx, 18 + k);
  }

  const float2* xb = (const float2*)(xT + (size_t)b * N * C);
  const float2* xpb = (const float2*)(xpT + (size_t)b * N * C);
  const float2* cs = cstat + (size_t)b * N;

  // ---- Phase 1: per-lane dot partials over this lane's 2 channels --------
  float p[K];
#pragma unroll
  for (int k = 0; k < K; ++k) p[k] = 0.f;
  if (lane < 48) {
#pragma unroll
    for (int k = 0; k < K; ++k) {
      const float2 a = xb[(size_t)ji[k] * 48 + lane];
      const float2 q = xb[(size_t)jj[k] * 48 + lane];
      p[k] = a.x * q.x + a.y * q.y;
    }
  }

  // ---- Phase 2: pairing-tree reduction (21 shuffles for 18 sums) ---------
  // pair(A,B,D): lanes with (lane&D)==0 end up carrying A's D-pair sum,
  // lanes with the bit set carry B's.
  auto pairstep = [&](float A, float Bv, int D) {
    const bool s = (lane & D) != 0;
    const float u = s ? Bv : A;
    const float v = s ? A : Bv;
    return u + __shfl_xor(v, D, 64);
  };
  float q_[9];
#pragma unroll
  for (int m = 0; m < 9; ++m) q_[m] = pairstep(p[2 * m], p[2 * m + 1], 32);
  float r_[5];
#pragma unroll
  for (int t = 0; t < 4; ++t) r_[t] = pairstep(q_[2 * t], q_[2 * t + 1], 16);
  r_[4] = q_[8] + __shfl_xor(q_[8], 16, 64);
  float s0 = pairstep(r_[0], r_[1], 8);
  float s1 = pairstep(r_[2], r_[3], 8);
  float s2 = r_[4] + __shfl_xor(r_[4], 8, 64);
  float t0 = pairstep(s0, s1, 4);
  float t1 = s2 + __shfl_xor(s2, 4, 64);
  float u0 = pairstep(t0, t1, 2);
  const float w = u0 + __shfl_xor(u0, 1, 64);
  // lane holding S_k: k<16 -> ((k&1)<<5)|((k&2)<<3)|((k&4)<<1)|((k&8)>>1);
  // k=16 -> 2; k=17 -> 34.

  // ---- Phase 3: sff per k (uniform) + fused xp accumulation --------------
  constexpr int LK[K] = {0, 32, 16, 48, 8,  40, 24, 56, 4,
                         36, 20, 52, 12, 44, 28, 60, 2,  34};
  if (lane < 48) {
    float accx = 0.f, accy = 0.f;
#pragma unroll
    for (int k = 0; k < K; ++k) {
      const float Sk = readlane_f(w, LK[k]);
      const float2 si = cs[ji[k]];
      const float2 sj = cs[jj[k]];
      const float mi = si.x * (1.0f / C), mj = sj.x * (1.0f / C);
      const float vi = si.y * (1.0f / C) - mi * mi;
      const float vj = sj.y * (1.0f / C) - mj * mj;
      const float cov = Sk * (1.0f / C) - mi * mj;
      const float S1 = (2.f * mi * mj + C1c) *
                       __builtin_amdgcn_rcpf(mi * mi + mj * mj + C1c);
      const float S2 =
          (2.f * cov + C2c) * __builtin_amdgcn_rcpf(vi + vj + C2c);
      const float sff = 1.f - S1 * S2;

      const float2 a = xpb[(size_t)ji[k] * 48 + lane];
      const float2 q = xpb[(size_t)jj[k] * 48 + lane];
      accx += a.x + q.x + fabsf(a.x - q.x) * sff;
      accy += a.y + q.y + fabsf(a.y - q.y) * sff;
    }
    float* ob = out + (size_t)b * C * N + n;
    ob[(size_t)(2 * lane) * N] = accx;
    ob[(size_t)(2 * lane + 1) * N] = accy;
  }
}

// ---------------------------------------------------------------------------
// Fallback (only used if ws_size is too small): slow but correct.
// ---------------------------------------------------------------------------
__global__ void fallback_kernel(const float* __restrict__ x,
                                const float* __restrict__ xp,
                                const int* __restrict__ e,
                                float* __restrict__ out) {
  const int gn = blockIdx.x * 64 + threadIdx.x;
  if (gn >= B * N) return;
  const int b = gn / N;
  const int n = gn - b * N;
  const float* xb = x + (size_t)b * C * N;
  const float* xpb = xp + (size_t)b * C * N;
  int ii[K], jj[K];
  float sff[K];
#pragma unroll
  for (int k = 0; k < K; ++k) {
    jj[k] = e[((size_t)(0 * B + b) * N + n) * K + k];
    ii[k] = e[((size_t)(1 * B + b) * N + n) * K + k];
    float si = 0, sj = 0, sii = 0, sjj = 0, sij = 0;
    for (int c = 0; c < C; ++c) {
      const float a = xb[(size_t)c * N + ii[k]];
      const float q = xb[(size_t)c * N + jj[k]];
      si += a; sj += q; sii += a * a; sjj += q * q; sij += a * q;
    }
    const float mi = si * (1.f / C), mj = sj * (1.f / C);
    const float vi = sii * (1.f / C) - mi * mi;
    const float vj = sjj * (1.f / C) - mj * mj;
    const float cov = sij * (1.f / C) - mi * mj;
    const float S1 = (2.f * mi * mj + C1c) / (mi * mi + mj * mj + C1c);
    const float S2 = (2.f * cov + C2c) / (vi + vj + C2c);
    sff[k] = 1.f - S1 * S2;
  }
  for (int c = 0; c < C; ++c) {
    float acc = 0.f;
#pragma unroll
    for (int k = 0; k < K; ++k) {
      const float a = xpb[(size_t)c * N + ii[k]];
      const float q = xpb[(size_t)c * N + jj[k]];
      acc += a + q + fabsf(a - q) * sff[k];
    }
    out[((size_t)b * C + c) * N + n] = acc;
  }
}

// ---------------------------------------------------------------------------
extern "C" void kernel_launch(void* const* d_in, const int* in_sizes, int n_in,
                              void* d_out, int out_size, void* d_ws, size_t ws_size,
                              hipStream_t stream) {
  const float* x = (const float*)d_in[0];
  const float* xp = (const float*)d_in[1];
  const int* e = (const int*)d_in[2];
  float* out = (float*)d_out;

  const size_t nBNC = (size_t)B * N * C;
  const size_t nBN = (size_t)B * N;
  const size_t need = 2 * nBNC * sizeof(float) + nBN * sizeof(float2);

  if (ws_size >= need) {
    float* ws = (float*)d_ws;
    float* xT = ws;
    float* xpT = xT + nBNC;
    float2* cstat = (float2*)(xpT + nBNC);

    transpose2_kernel<<<dim3(N / 32, C / 32, B), dim3(32, 8), 0, stream>>>(
        x, xp, xT, xpT);
    colstats_kernel<<<(B * N + 255) / 256, 256, 0, stream>>>(x, cstat);
    ssim_main_kernel<<<(B * N) / 4, 256, 0, stream>>>(xT, xpT, cstat, e, out);
  } else {
    fallback_kernel<<<(B * N + 63) / 64, 64, 0, stream>>>(x, xp, e, out);
  }
}

// Round 4
// 54.057 us; speedup vs baseline: 1.6339x; 1.6339x over previous
//
#include <hip/hip_runtime.h>
#include <cstdint>
#include <cstddef>

// Problem constants (from reference)
constexpr int B = 8, C = 96, N = 3136, K = 18;
constexpr float C1c = 1e-6f, C2c = 1e-6f;

__device__ inline float readlane_f(float v, int l) {
  return __builtin_bit_cast(float,
                            __builtin_amdgcn_readlane(__builtin_bit_cast(int, v), l));
}

// ---------------------------------------------------------------------------
// Kernel A (fused): transpose x,xp [B,C,N]->[B,N,C] AND per-column channel
// sums of x (cstat = {Σx, Σx²}). One block per 32 columns of one batch;
// XCD-pinned: blockIdx&7 == batch. Reads x once (was twice in R2).
// ---------------------------------------------------------------------------
__global__ __launch_bounds__(256) void fusedT_kernel(
    const float* __restrict__ x, const float* __restrict__ xp,
    float* __restrict__ xT, float* __restrict__ xpT,
    float2* __restrict__ cstat) {
  __shared__ float t0[C][33];
  __shared__ float t1[C][33];
  __shared__ float red1[8][33];
  __shared__ float red2[8][33];
  const int bid = blockIdx.x;
  const int b = bid & 7;              // XCD pin
  const int n0 = (bid >> 3) * 32;
  const int tx = threadIdx.x & 31;
  const int ty = threadIdx.x >> 5;

  const float* xb = x + (size_t)b * C * N;
  const float* xpb = xp + (size_t)b * C * N;
  float s = 0.f, s2 = 0.f;
#pragma unroll
  for (int st = 0; st < 12; ++st) {
    const int c = st * 8 + ty;
    const float v = xb[(size_t)c * N + n0 + tx];
    const float u = xpb[(size_t)c * N + n0 + tx];
    t0[c][tx] = v;
    t1[c][tx] = u;
    s += v;
    s2 += v * v;
  }
  red1[ty][tx] = s;
  red2[ty][tx] = s2;
  __syncthreads();

  float* xTb = xT + (size_t)b * N * C;
  float* xpTb = xpT + (size_t)b * N * C;
  const int tid = threadIdx.x;
#pragma unroll
  for (int r = 0; r < 12; ++r) {
    const int f = r * 256 + tid;      // f = nl*96 + c, coalesced
    const int nl = f / 96;
    const int c = f - nl * 96;
    xTb[(size_t)(n0 + nl) * C + c] = t0[c][nl];
    xpTb[(size_t)(n0 + nl) * C + c] = t1[c][nl];
  }
  if (ty == 0) {
    float S = 0.f, S2 = 0.f;
#pragma unroll
    for (int yy = 0; yy < 8; ++yy) {
      S += red1[yy][tx];
      S2 += red2[yy][tx];
    }
    cstat[(size_t)b * N + n0 + tx] = make_float2(S, S2);
  }
}

// ---------------------------------------------------------------------------
// Kernel B: main fused kernel. One wave per (b,n); XCD-pinned (blockIdx&7=b).
// Phase 1: GROUP-PARALLEL dots — lane = 8g+w; group g owns k = {g,g+8,g+16};
//   lane loads 12 channels (3x float4) of columns i_k,j_k; 3-level butterfly
//   within the 8-lane group. 15 bpermutes/wave total (vs 108 in R2) with
//   8-way parallelism and 3 independent rounds of ILP.
//   sff for 8 k's computed at once per round (group-parallel), then
//   broadcast to SGPRs via 18 readlanes.
// Phase 2: R2's proven xp accumulation (lane c + masked c+64), coalesced
//   write to outT[B,N,C].
// ---------------------------------------------------------------------------
__global__ __launch_bounds__(256) void ssim_main_kernel(
    const float* __restrict__ xT, const float* __restrict__ xpT,
    const float2* __restrict__ cstat, const int* __restrict__ eidx,
    float* __restrict__ outT) {
  const int wave = threadIdx.x >> 6;
  const int lane = threadIdx.x & 63;
  const int b = blockIdx.x & 7;       // XCD pin: batch == blockIdx % 8
  const int tile = blockIdx.x >> 3;
  const int n = tile * 4 + wave;

  // lanes 0..17 -> j_k (edge_index[0]), lanes 18..35 -> i_k (edge_index[1])
  int myidx = 0;
  if (lane < 36) {
    const int s = (lane >= 18) ? 1 : 0;
    const int k = lane - 18 * s;
    myidx = eidx[((size_t)(s * B + b) * N + n) * K + k];
  }

  const float* xb = xT + (size_t)b * N * C;
  const float* xpb = xpT + (size_t)b * N * C;
  const float2* cs = cstat + (size_t)b * N;

  const int g = lane >> 3;
  const int w = lane & 7;

  // ---- Phase 1: grouped dot products + group-parallel sff ----------------
  float sffr[3];
#pragma unroll
  for (int r = 0; r < 3; ++r) {
    int k = r * 8 + g;
    if (k > K - 1) k = K - 1;         // groups 2..7 in round 2: redundant k=17
    const int cj = __shfl(myidx, k, 64);        // per-lane src -> bpermute
    const int ci = __shfl(myidx, 18 + k, 64);
    const float* pi = xb + (size_t)ci * C + w * 12;
    const float* pj = xb + (size_t)cj * C + w * 12;
    const float4 a0 = *(const float4*)pi;
    const float4 a1 = *(const float4*)(pi + 4);
    const float4 a2 = *(const float4*)(pi + 8);
    const float4 q0 = *(const float4*)pj;
    const float4 q1 = *(const float4*)(pj + 4);
    const float4 q2 = *(const float4*)(pj + 8);
    float p = a0.x * q0.x + a0.y * q0.y + a0.z * q0.z + a0.w * q0.w;
    p += a1.x * q1.x + a1.y * q1.y + a1.z * q1.z + a1.w * q1.w;
    p += a2.x * q2.x + a2.y * q2.y + a2.z * q2.z + a2.w * q2.w;
    p += __shfl_xor(p, 1, 64);        // butterfly within the 8-lane group
    p += __shfl_xor(p, 2, 64);
    p += __shfl_xor(p, 4, 64);

    const float2 si = cs[ci];
    const float2 sj = cs[cj];
    const float mi = si.x * (1.0f / C), mj = sj.x * (1.0f / C);
    const float vi = si.y * (1.0f / C) - mi * mi;
    const float vj = sj.y * (1.0f / C) - mj * mj;
    const float cov = p * (1.0f / C) - mi * mj;
    const float S1 =
        (2.f * mi * mj + C1c) * __builtin_amdgcn_rcpf(mi * mi + mj * mj + C1c);
    const float S2 = (2.f * cov + C2c) * __builtin_amdgcn_rcpf(vi + vj + C2c);
    sffr[r] = 1.f - S1 * S2;
  }

  // Broadcast sff_k to wave-uniform SGPRs (group g's first lane is 8*(k&7))
  float sk[K];
#pragma unroll
  for (int k = 0; k < K; ++k) sk[k] = readlane_f(sffr[k >> 3], (k & 7) * 8);

  // Wave-uniform column indices for the xp phase
  int jjs[K], jis[K];
#pragma unroll
  for (int k = 0; k < K; ++k) {
    jjs[k] = __builtin_amdgcn_readlane(myidx, k);
    jis[k] = __builtin_amdgcn_readlane(myidx, 18 + k);
  }

  // ---- Phase 2: xp accumulation (R2 structure), coalesced outT write -----
  const int c1 = lane;
  const int c2 = (lane < 32) ? lane + 64 : 95;
  float acc1 = 0.f, acc2 = 0.f;
#pragma unroll
  for (int k = 0; k < K; ++k) {
    const float* pi = xpb + (size_t)jis[k] * C;
    const float* pj = xpb + (size_t)jjs[k] * C;
    const float sff = sk[k];
    const float a1 = pi[c1], q1 = pj[c1];
    acc1 += a1 + q1 + fabsf(a1 - q1) * sff;
    const float a2 = pi[c2], q2 = pj[c2];
    acc2 += a2 + q2 + fabsf(a2 - q2) * sff;
  }
  float* ob = outT + ((size_t)b * N + n) * C;
  ob[c1] = acc1;
  if (lane < 32) ob[c2] = acc2;
}

// ---------------------------------------------------------------------------
// Kernel C: transpose back outT [B,N,C] -> out [B,C,N], XCD-pinned.
// ---------------------------------------------------------------------------
__global__ __launch_bounds__(256) void transpose_back_kernel(
    const float* __restrict__ outT, float* __restrict__ out) {
  __shared__ float t[32][33];
  const int bid = blockIdx.x;
  const int b = bid & 7;              // XCD pin
  const int rest = bid >> 3;          // 0..293
  const int cb = rest / 98;           // 0..2
  const int nb = rest - cb * 98;      // 0..97
  const int n0 = nb * 32, c0 = cb * 32;
  const int tx = threadIdx.x & 31, ty = threadIdx.x >> 5;
  const float* ib = outT + (size_t)b * N * C;
#pragma unroll
  for (int i = 0; i < 4; ++i) {
    const int nn = n0 + ty + i * 8;
    t[ty + i * 8][tx] = ib[(size_t)nn * C + c0 + tx];
  }
  __syncthreads();
  float* ob = out + (size_t)b * C * N;
#pragma unroll
  for (int i = 0; i < 4; ++i) {
    const int c = c0 + ty + i * 8;
    ob[(size_t)c * N + n0 + tx] = t[tx][ty + i * 8];
  }
}

// ---------------------------------------------------------------------------
// Fallback (only used if ws_size is too small): slow but correct.
// ---------------------------------------------------------------------------
__global__ void fallback_kernel(const float* __restrict__ x,
                                const float* __restrict__ xp,
                                const int* __restrict__ e,
                                float* __restrict__ out) {
  const int gn = blockIdx.x * 64 + threadIdx.x;
  if (gn >= B * N) return;
  const int b = gn / N;
  const int n = gn - b * N;
  const float* xb = x + (size_t)b * C * N;
  const float* xpb = xp + (size_t)b * C * N;
  int ii[K], jj[K];
  float sff[K];
#pragma unroll
  for (int k = 0; k < K; ++k) {
    jj[k] = e[((size_t)(0 * B + b) * N + n) * K + k];
    ii[k] = e[((size_t)(1 * B + b) * N + n) * K + k];
    float si = 0, sj = 0, sii = 0, sjj = 0, sij = 0;
    for (int c = 0; c < C; ++c) {
      const float a = xb[(size_t)c * N + ii[k]];
      const float q = xb[(size_t)c * N + jj[k]];
      si += a; sj += q; sii += a * a; sjj += q * q; sij += a * q;
    }
    const float mi = si * (1.f / C), mj = sj * (1.f / C);
    const float vi = sii * (1.f / C) - mi * mi;
    const float vj = sjj * (1.f / C) - mj * mj;
    const float cov = sij * (1.f / C) - mi * mj;
    const float S1 = (2.f * mi * mj + C1c) / (mi * mi + mj * mj + C1c);
    const float S2 = (2.f * cov + C2c) / (vi + vj + C2c);
    sff[k] = 1.f - S1 * S2;
  }
  for (int c = 0; c < C; ++c) {
    float acc = 0.f;
#pragma unroll
    for (int k = 0; k < K; ++k) {
      const float a = xpb[(size_t)c * N + ii[k]];
      const float q = xpb[(size_t)c * N + jj[k]];
      acc += a + q + fabsf(a - q) * sff[k];
    }
    out[((size_t)b * C + c) * N + n] = acc;
  }
}

// ---------------------------------------------------------------------------
extern "C" void kernel_launch(void* const* d_in, const int* in_sizes, int n_in,
                              void* d_out, int out_size, void* d_ws, size_t ws_size,
                              hipStream_t stream) {
  const float* x = (const float*)d_in[0];
  const float* xp = (const float*)d_in[1];
  const int* e = (const int*)d_in[2];
  float* out = (float*)d_out;

  const size_t nBNC = (size_t)B * N * C;
  const size_t nBN = (size_t)B * N;
  const size_t need = 3 * nBNC * sizeof(float) + nBN * sizeof(float2);

  if (ws_size >= need) {
    float* ws = (float*)d_ws;
    float* xT = ws;
    float* xpT = xT + nBNC;
    float* outT = xpT + nBNC;
    float2* cstat = (float2*)(outT + nBNC);

    fusedT_kernel<<<8 * (N / 32), 256, 0, stream>>>(x, xp, xT, xpT, cstat);
    ssim_main_kernel<<<(B * N) / 4, 256, 0, stream>>>(xT, xpT, cstat, e, outT);
    transpose_back_kernel<<<8 * 3 * (N / 32), 256, 0, stream>>>(outT, out);
  } else {
    fallback_kernel<<<(B * N + 63) / 64, 64, 0, stream>>>(x, xp, e, out);
  }
}